// Round 11
// baseline (463.687 us; speedup 1.0000x reference)
//
#include <hip/hip_runtime.h>
#include <hip/hip_bf16.h>

#define N 8192
#define IN_F 128
#define OUT_F 64
#define LRELU_ALPHA 0.2f
#define SPLIT 4    // column splits
#define RPB 64     // rows per block
#define CPB 2048   // cols per block = N/SPLIT
#define WIN 512    // cols per window
#define NWIN 4     // CPB/WIN
#define TSTR 129   // granules per p-tile row (128 + 1 pad -> conflict-free)

typedef __attribute__((ext_vector_type(8))) short short8;
typedef __attribute__((ext_vector_type(4))) short short4v;
typedef __attribute__((ext_vector_type(4))) float float4v;
typedef __attribute__((ext_vector_type(4))) unsigned short ushortx4;
typedef unsigned long long u64;

__device__ __forceinline__ unsigned short bf16_bits(float x) {
  unsigned u = __builtin_bit_cast(unsigned, x);
  u += 0x7fffu + ((u >> 16) & 1u);  // round-to-nearest-even
  return (unsigned short)(u >> 16);
}

// prep: Wh = h@W (fp32), s1 = Wh@a1, s2 = Wh@a2, whT bf16 [64][8192]
__global__ __launch_bounds__(256) void prep_kernel(
    const float* __restrict__ h, const float* __restrict__ W,
    const float* __restrict__ a, float* __restrict__ s1,
    float* __restrict__ s2, unsigned short* __restrict__ whT) {
  const int tid = threadIdx.x;
  const int row = blockIdx.x * 4 + (tid >> 6);
  const int k = tid & 63;
  const float* hr = h + row * IN_F;
  float acc = 0.f;
#pragma unroll 8
  for (int c = 0; c < IN_F; ++c) acc = fmaf(hr[c], W[c * OUT_F + k], acc);
  whT[(long)k * N + row] = bf16_bits(acc);
  float p1 = acc * a[k];
  float p2 = acc * a[OUT_F + k];
#pragma unroll
  for (int off = 32; off > 0; off >>= 1) {
    p1 += __shfl_xor(p1, off);
    p2 += __shfl_xor(p2, off);
  }
  if (k == 0) { s1[row] = p1; s2[row] = p2; }
}

// repack whT [64][8192] -> B-fragment order: whF[(c32*256 + tt*64 + lane)*8]
__global__ __launch_bounds__(256) void repack_kernel(
    const unsigned short* __restrict__ whT, unsigned short* __restrict__ whF) {
  const int f = blockIdx.x * 256 + threadIdx.x;  // 0..65535 fragments
  const int lane = f & 63, tt = (f >> 6) & 3, c = f >> 8;
  const int r16 = lane & 15, quad = lane >> 4;
  const short8 v = *(const short8*)(whT + (long)(tt * 16 + r16) * N + c * 32 + quad * 8);
  *(short8*)(whF + (long)f * 8) = v;
}

// Bit-pack adj: 256MB int32 -> 8MB bitmask. Pure streaming read (int4/lane,
// 1KB per wave-instr, no LDS/barriers). pk[row*128 + cc*4 + i] bit L =
// (adj[row][cc*256 + 4L + i] > 0). This is also the isolating probe for the
// adj-read ceiling: dur(pack) == achievable 256MB read time.
__global__ __launch_bounds__(256) void pack_kernel(
    const int* __restrict__ adj, u64* __restrict__ pk) {
  const int tid = threadIdx.x;
  const int w = tid >> 6, L = tid & 63;
  const int row = blockIdx.x * 4 + w;
  const int* rp = adj + (long)row * N;
  u64* dst = pk + (long)row * 128;
#pragma unroll 4
  for (int cc = 0; cc < 32; ++cc) {
    const int4 a = *(const int4*)(rp + cc * 256 + L * 4);
    const u64 b0 = __ballot(a.x > 0);
    const u64 b1 = __ballot(a.y > 0);
    const u64 b2 = __ballot(a.z > 0);
    const u64 b3 = __ballot(a.w > 0);
    if (L == 0) {
      dst[cc * 4 + 0] = b0;
      dst[cc * 4 + 1] = b1;
      dst[cc * 4 + 2] = b2;
      dst[cc * 4 + 3] = b3;
    }
  }
}

// compute 4 p's from mask bits (bit L of q0..q3), write one 8B granule
__device__ __forceinline__ float p_half(unsigned short* dst, u64 q0, u64 q1,
                                        u64 q2, u64 q3, float4 s2v, float s1w,
                                        int L) {
  float e0 = s1w + s2v.x; e0 = fmaxf(e0, LRELU_ALPHA * e0);
  float e1 = s1w + s2v.y; e1 = fmaxf(e1, LRELU_ALPHA * e1);
  float e2 = s1w + s2v.z; e2 = fmaxf(e2, LRELU_ALPHA * e2);
  float e3 = s1w + s2v.w; e3 = fmaxf(e3, LRELU_ALPHA * e3);
  const float p0 = ((q0 >> L) & 1) ? __expf(e0) : 0.f;
  const float p1 = ((q1 >> L) & 1) ? __expf(e1) : 0.f;
  const float p2 = ((q2 >> L) & 1) ? __expf(e2) : 0.f;
  const float p3 = ((q3 >> L) & 1) ? __expf(e3) : 0.f;
  ushortx4 pkv = {bf16_bits(p0), bf16_bits(p1), bf16_bits(p2), bf16_bits(p3)};
  *(ushortx4*)dst = pkv;
  return (p0 + p1) + (p2 + p3);
}

// Fused GAT partial from PACKED adj: grid (128 rowtiles, 4 colsplits) x 512
// thr (8 waves). Identical to the round-10 structure (verified correct) but
// the 512KB/block adj stream is replaced by 16KB/block mask broadcasts --
// per (row, 256-col chunk) all lanes read the same 32B of ballots; lane L
// uses bit L. s2 in LDS; whF read once per block; p-tile granule layout.
__global__ __launch_bounds__(512, 4) void gat_kernel(
    const u64* __restrict__ pk, const float* __restrict__ s1,
    const float* __restrict__ s2, const unsigned short* __restrict__ whF,
    float* __restrict__ pacc, float* __restrict__ pl) {
  __shared__ __align__(16) unsigned short ptile[RPB * TSTR * 4];  // 66048B
  __shared__ __align__(16) float s2l[CPB];                        // 8192B
  const int tid = threadIdx.x;
  const int w = tid >> 6, L = tid & 63;
  const int r16 = L & 15, quad = L >> 4;
  const int rb = blockIdx.x, cs = blockIdx.y;
  const int row0 = rb * RPB;
  const int colbase = cs * CPB;

  *(float4*)(s2l + tid * 4) = *(const float4*)(s2 + colbase + tid * 4);

  float s1r[8];  // wave-uniform -> scalar loads
#pragma unroll
  for (int j = 0; j < 8; ++j) s1r[j] = s1[row0 + w * 8 + j];

  float lsum[8] = {0.f, 0.f, 0.f, 0.f, 0.f, 0.f, 0.f, 0.f};
  float4v acc[4][4];
#pragma unroll
  for (int rt = 0; rt < 4; ++rt)
#pragma unroll
    for (int dt = 0; dt < 4; ++dt) acc[rt][dt] = (float4v){0.f, 0.f, 0.f, 0.f};

  __syncthreads();  // s2l ready

  for (int it = 0; it < NWIN; ++it) {
    // ---- produce: rows w*8..w*8+7, cols it*512 + {L*4, 256+L*4} ----
    const int c0 = it * WIN + L * 4;
    const float4 sva = *(const float4*)(s2l + c0);
    const float4 svb = *(const float4*)(s2l + c0 + 256);
#pragma unroll
    for (int r = 0; r < 8; ++r) {
      const u64* mp = pk + (long)(row0 + w * 8 + r) * 128 + (cs * 8 + it * 2) * 4;
      const ulonglong2 qa = *(const ulonglong2*)(mp);      // chunk cc0 ballots 0,1
      const ulonglong2 qb = *(const ulonglong2*)(mp + 2);  // chunk cc0 ballots 2,3
      const ulonglong2 qc = *(const ulonglong2*)(mp + 4);  // chunk cc0+1 ballots 0,1
      const ulonglong2 qd = *(const ulonglong2*)(mp + 6);  // chunk cc0+1 ballots 2,3
      unsigned short* rowp = ptile + (w * 8 + r) * TSTR * 4;
      lsum[r] += p_half(rowp + L * 4, qa.x, qa.y, qb.x, qb.y, sva, s1r[r], L);
      lsum[r] += p_half(rowp + (64 + L) * 4, qc.x, qc.y, qd.x, qd.y, svb, s1r[r], L);
    }
    __syncthreads();  // p-tile published
    // ---- consume: wave w owns chunks {w, w+8}, all 4 row-tiles ----
#pragma unroll
    for (int ci = 0; ci < 2; ++ci) {
      const int c = w + ci * 8;
      const unsigned short* bp =
          whF + ((long)(cs * 64 + it * 16 + c) * 256 + L) * 8;
      const short8 b0 = *(const short8*)(bp);
      const short8 b1 = *(const short8*)(bp + 512);
      const short8 b2 = *(const short8*)(bp + 1024);
      const short8 b3 = *(const short8*)(bp + 1536);
#pragma unroll
      for (int rt = 0; rt < 4; ++rt) {
        const int g = (rt * 16 + r16) * TSTR + c * 8 + quad * 2;
        const short4v alo = *(const short4v*)(ptile + g * 4);
        const short4v ahi = *(const short4v*)(ptile + g * 4 + 4);
        const short8 afrag =
            __builtin_shufflevector(alo, ahi, 0, 1, 2, 3, 4, 5, 6, 7);
        acc[rt][0] = __builtin_amdgcn_mfma_f32_16x16x32_bf16(afrag, b0, acc[rt][0], 0, 0, 0);
        acc[rt][1] = __builtin_amdgcn_mfma_f32_16x16x32_bf16(afrag, b1, acc[rt][1], 0, 0, 0);
        acc[rt][2] = __builtin_amdgcn_mfma_f32_16x16x32_bf16(afrag, b2, acc[rt][2], 0, 0, 0);
        acc[rt][3] = __builtin_amdgcn_mfma_f32_16x16x32_bf16(afrag, b3, acc[rt][3], 0, 0, 0);
      }
    }
    __syncthreads();  // reads drained before next window overwrites p-tile
  }

  // denominators: reduce each of 8 row-sums across the wave
#pragma unroll
  for (int j = 0; j < 8; ++j) {
    float v = lsum[j];
#pragma unroll
    for (int off = 1; off < 64; off <<= 1) v += __shfl_xor(v, off);
    if (L == 0) pl[(long)cs * N + row0 + w * 8 + j] = v;
  }

  // K-merge across 8 waves in LDS (4 slots x 4096 floats = 64KB <= ptile)
  float* M = (float*)ptile;
  if (w >= 4) {
    float* S = M + (w - 4) * 4096;
#pragma unroll
    for (int rt = 0; rt < 4; ++rt)
#pragma unroll
      for (int dt = 0; dt < 4; ++dt)
#pragma unroll
        for (int reg = 0; reg < 4; ++reg)
          S[(rt * 16 + quad * 4 + reg) * 64 + dt * 16 + r16] = acc[rt][dt][reg];
  }
  __syncthreads();
  if (w < 4) {
    float* S = M + w * 4096;
#pragma unroll
    for (int rt = 0; rt < 4; ++rt)
#pragma unroll
      for (int dt = 0; dt < 4; ++dt)
#pragma unroll
        for (int reg = 0; reg < 4; ++reg)
          S[(rt * 16 + quad * 4 + reg) * 64 + dt * 16 + r16] += acc[rt][dt][reg];
  }
  __syncthreads();
#pragma unroll
  for (int o = tid; o < 1024; o += 512) {
    const int r = o >> 4, k4 = (o & 15) * 4;
    float4 v0 = *(const float4*)(M + 0 * 4096 + r * 64 + k4);
    const float4 v1 = *(const float4*)(M + 1 * 4096 + r * 64 + k4);
    const float4 v2 = *(const float4*)(M + 2 * 4096 + r * 64 + k4);
    const float4 v3 = *(const float4*)(M + 3 * 4096 + r * 64 + k4);
    v0.x += v1.x + v2.x + v3.x;
    v0.y += v1.y + v2.y + v3.y;
    v0.z += v1.z + v2.z + v3.z;
    v0.w += v1.w + v2.w + v3.w;
    *(float4*)(pacc + ((long)cs * N + row0 + r) * OUT_F + k4) = v0;
  }
}

// merge SPLIT partials, normalize, elu
__global__ __launch_bounds__(256) void merge_kernel(
    const float* __restrict__ pacc, const float* __restrict__ pl,
    float* __restrict__ out) {
  const int idx = blockIdx.x * 256 + threadIdx.x;  // 0..131071
  const int r = idx >> 4;
  const int k4 = (idx & 15) * 4;
  float4 S = {0.f, 0.f, 0.f, 0.f};
  float Lx = 0.f;
#pragma unroll
  for (int c = 0; c < SPLIT; ++c) {
    const float4 p = *(const float4*)(pacc + ((long)c * N + r) * OUT_F + k4);
    S.x += p.x; S.y += p.y; S.z += p.z; S.w += p.w;
    Lx += pl[(long)c * N + r];
  }
  const float inv = 1.f / Lx;
  float v[4] = {S.x * inv, S.y * inv, S.z * inv, S.w * inv};
  float4 o;
  o.x = v[0] > 0.f ? v[0] : expm1f(v[0]);
  o.y = v[1] > 0.f ? v[1] : expm1f(v[1]);
  o.z = v[2] > 0.f ? v[2] : expm1f(v[2]);
  o.w = v[3] > 0.f ? v[3] : expm1f(v[3]);
  *(float4*)(out + (long)r * OUT_F + k4) = o;
}

extern "C" void kernel_launch(void* const* d_in, const int* in_sizes, int n_in,
                              void* d_out, int out_size, void* d_ws, size_t ws_size,
                              hipStream_t stream) {
  const float* h = (const float*)d_in[0];
  const int* adj = (const int*)d_in[1];
  const float* W = (const float*)d_in[2];
  const float* a = (const float*)d_in[3];
  float* out = (float*)d_out;

  // ws: s1[8192] | s2[8192] | whT[64*8192] bf16 | whF[64*8192] bf16 |
  //     pacc[SPLIT][8192][64] f32 (8MB) | pl[SPLIT][8192] f32 | pk[8192*128] u64 (8MB)
  float* s1 = (float*)d_ws;
  float* s2 = s1 + N;
  unsigned short* whT = (unsigned short*)(s2 + N);
  unsigned short* whF = whT + (long)OUT_F * N;
  float* pacc = (float*)(whF + (long)OUT_F * N);
  float* pl = pacc + (long)SPLIT * N * OUT_F;
  u64* pk = (u64*)(pl + (long)SPLIT * N);

  prep_kernel<<<N / 4, 256, 0, stream>>>(h, W, a, s1, s2, whT);
  repack_kernel<<<N * OUT_F / 8 / 256, 256, 0, stream>>>(whT, whF);
  pack_kernel<<<N / 4, 256, 0, stream>>>(adj, pk);
  gat_kernel<<<dim3(N / RPB, SPLIT), 512, 0, stream>>>(pk, s1, s2, whF, pacc, pl);
  merge_kernel<<<N * OUT_F / 4 / 256, 256, 0, stream>>>(pacc, pl, out);
}